// Round 19
// baseline (103.005 us; speedup 1.0000x reference)
//
#include <hip/hip_runtime.h>

// out[n,k] = d[k] + sum_{ji,c} Bt[ji*512+c][k] * bilinear_ji(proj[n,c,:,:])
// Bt = transpose of WH·(w3·w2·w1), k-major padded to 12.
//
// k_mainf v3: barrier-free. Block (n, half); wave w privately owns channels
// {4w..4w+3} of each 16-channel chunk in its own LDS double-buffer -> no
// s_barrier at all, waves self-pace. Per chunk: coeff loads issued FIRST,
// then next-chunk proj loads (so coeff use waits vmcnt(4), proj survives),
// sched_barrier, compute (LDS+regs only), scatter next chunk.
//
// ws layout (floats):
//   WH    [490][512]     off 0
//   Y     [512][512]     off 250880
//   T1    [490][512]     off 513024
//   Bt    [25088][12]    off 763904
//   u2    [512]          off 1064960
//   vv    [512]          off 1065472
//   dpart [10][8]        off 1065984
//   part  [1024*4][10]   off 1066064

#define CHW4 25088   // float4 per proj row
#define STEP 1.8571428571428572f  // 13/7

// ---------- prep level 1: WH transpose (blocks 0..489) + u2=b2+w2*b1 (490..553)
__global__ __launch_bounds__(512) void k_prep1(
    const float* __restrict__ w_note, const float* __restrict__ w_reg,
    const float* __restrict__ w2, const float* __restrict__ b1,
    const float* __restrict__ b2,
    float* __restrict__ WH, float* __restrict__ u2) {
    int blk = blockIdx.x;
    int tid = threadIdx.x;
    if (blk < 490) {
        int k = blk / 49, ji = blk % 49;
        const float* wh = (k < 2) ? (w_note + k * 25088) : (w_reg + (k - 2) * 25088);
        WH[(size_t)blk * 512 + tid] = wh[tid * 49 + ji];
    } else {
        int wv = tid >> 6, lane = tid & 63;
        int o = (blk - 490) * 8 + wv;
        float s = 0.f;
        #pragma unroll
        for (int r = 0; r < 8; ++r) s += w2[(size_t)o * 512 + lane + r * 64] * b1[lane + r * 64];
        for (int off = 32; off; off >>= 1) s += __shfl_down(s, off);
        if (lane == 0) u2[o] = b2[o] + s;
    }
}

// ---------- prep level 2: {Y=w2*w1 | T1=WH*w3} (0..511) + vv=b3+w3*u2 (512..639)
__global__ __launch_bounds__(256) void k_prep2(
    const float* __restrict__ w1, const float* __restrict__ w2,
    const float* __restrict__ w3, const float* __restrict__ WH,
    const float* __restrict__ u2, const float* __restrict__ b3,
    float* __restrict__ Y, float* __restrict__ T1, float* __restrict__ vv) {
    int blk = blockIdx.x;
    int tid = threadIdx.x;
    if (blk < 512) {
        __shared__ float As[32][36];
        __shared__ float Bs[32][36];
        const float* A; const float* B; float* C; int M;
        if (blk < 256) { A = w2; B = w1; C = Y;  M = 512; }
        else           { A = WH; B = w3; C = T1; M = 490; }
        int t = blk & 255;
        int bx = t & 15, by = t >> 4;
        int lr = tid >> 3, lc = (tid & 7) << 2;
        int tx = tid & 15, ty = tid >> 4;
        float a00 = 0.f, a01 = 0.f, a10 = 0.f, a11 = 0.f;
        for (int kc = 0; kc < 512; kc += 32) {
            int gr = by * 32 + lr;
            float4 av = make_float4(0.f, 0.f, 0.f, 0.f);
            if (gr < M) av = *(const float4*)&A[(size_t)gr * 512 + kc + lc];
            *(float4*)&As[lr][lc] = av;
            *(float4*)&Bs[lr][lc] = *(const float4*)&B[(size_t)(kc + lr) * 512 + bx * 32 + lc];
            __syncthreads();
            #pragma unroll
            for (int kk = 0; kk < 32; ++kk) {
                float b0 = Bs[kk][tx * 2], b1v = Bs[kk][tx * 2 + 1];
                float x0 = As[ty * 2][kk], x1 = As[ty * 2 + 1][kk];
                a00 += x0 * b0; a01 += x0 * b1v;
                a10 += x1 * b0; a11 += x1 * b1v;
            }
            __syncthreads();
        }
        int r0 = by * 32 + ty * 2, c0 = bx * 32 + tx * 2;
        if (r0 < M)     { C[(size_t)r0 * 512 + c0] = a00; C[(size_t)r0 * 512 + c0 + 1] = a01; }
        if (r0 + 1 < M) { C[(size_t)(r0 + 1) * 512 + c0] = a10; C[(size_t)(r0 + 1) * 512 + c0 + 1] = a11; }
    } else {
        int wv = tid >> 6, lane = tid & 63;
        int o = (blk - 512) * 4 + wv;
        float s = 0.f;
        #pragma unroll
        for (int r = 0; r < 8; ++r) s += w3[(size_t)o * 512 + lane + r * 64] * u2[lane + r * 64];
        for (int off = 32; off; off >>= 1) s += __shfl_down(s, off);
        if (lane == 0) vv[o] = b3[o] + s;
    }
}

// ---------- prep level 3: Bt = transpose(T1*Y) k-major (0..255) + dpart (256..335)
__global__ __launch_bounds__(256) void k_prep3(
    const float* __restrict__ T1, const float* __restrict__ Y,
    const float* __restrict__ w_note, const float* __restrict__ w_reg,
    const float* __restrict__ vv,
    float* __restrict__ Bt, float* __restrict__ dpart) {
    int blk = blockIdx.x;
    int tid = threadIdx.x;
    if (blk < 256) {
        __shared__ float As[32][36];
        __shared__ float Bs[32][36];
        int bx = blk & 15, by = blk >> 4;
        int lr = tid >> 3, lc = (tid & 7) << 2;
        int tx = tid & 15, ty = tid >> 4;
        int gr = by * 32 + lr;
        float a00 = 0.f, a01 = 0.f, a10 = 0.f, a11 = 0.f;
        for (int kc = 0; kc < 512; kc += 32) {
            float4 av = make_float4(0.f, 0.f, 0.f, 0.f);
            if (gr < 490) av = *(const float4*)&T1[(size_t)gr * 512 + kc + lc];
            *(float4*)&As[lr][lc] = av;
            *(float4*)&Bs[lr][lc] = *(const float4*)&Y[(size_t)(kc + lr) * 512 + bx * 32 + lc];
            __syncthreads();
            #pragma unroll
            for (int kk = 0; kk < 32; ++kk) {
                float b0 = Bs[kk][tx * 2], b1v = Bs[kk][tx * 2 + 1];
                float x0 = As[ty * 2][kk], x1 = As[ty * 2 + 1][kk];
                a00 += x0 * b0; a01 += x0 * b1v;
                a10 += x1 * b0; a11 += x1 * b1v;
            }
            __syncthreads();
        }
        int r0 = by * 32 + ty * 2, c0 = bx * 32 + tx * 2;
        if (r0 < 490) {
            int k = r0 / 49, ji = r0 - k * 49;
            Bt[((size_t)(ji * 512 + c0)) * 12 + k] = a00;
            Bt[((size_t)(ji * 512 + c0 + 1)) * 12 + k] = a01;
        }
        if (r0 + 1 < 490) {
            int k = (r0 + 1) / 49, ji = (r0 + 1) - k * 49;
            Bt[((size_t)(ji * 512 + c0)) * 12 + k] = a10;
            Bt[((size_t)(ji * 512 + c0 + 1)) * 12 + k] = a11;
        }
    } else {
        int t = blk - 256;             // 0..79
        int k = t >> 3, b8 = t & 7;
        const float* wh = (k < 2) ? (w_note + k * 25088) : (w_reg + (k - 2) * 25088);
        float s = 0.f;
        for (int i = b8 * 256 + tid; i < 25088; i += 2048) s += wh[i] * vv[i / 49];
        __shared__ float red[256];
        red[tid] = s;
        __syncthreads();
        for (int off = 128; off; off >>= 1) {
            if (tid < off) red[tid] += red[tid + off];
            __syncthreads();
        }
        if (tid == 0) dpart[k * 8 + b8] = red[0];
    }
}

// ---------- fused main v3: wave-private LDS, no barriers, coeff-first issue
__global__ __launch_bounds__(256) void k_mainf(const float* __restrict__ proj,
                                               const float* __restrict__ Bt,
                                               float* __restrict__ part) {
    __shared__ float X[4][2][788];    // wave-private double buffers; 25,216 B
    int b = blockIdx.x;               // 0..1023
    int n = b >> 1;
    int ch0 = (b & 1) << 4;           // chunk ch = ch0 + t
    int tid = threadIdx.x;
    int wv = tid >> 6, lane = tid & 63;

    // staging scatter coords: fi = r*64 + lane = cc*49 + q  (cc in 0..3)
    int cc0 = lane / 49, q0 = lane - cc0 * 49;
    int cc1 = cc0 + 1, q1 = q0 + 15; if (q1 >= 49) { q1 -= 49; ++cc1; }
    int cc2 = cc1 + 1, q2 = q1 + 15; if (q2 >= 49) { q2 -= 49; ++cc2; }
    bool l4 = lane < 4;
    int q3 = 45 + lane;               // cc = 3, lanes 0..3 only

    // chunk-invariant slot coords: slot = s*64+lane (s<3) and 192+lane (lane<4)
    const float base = STEP * 0.5f - 0.5f;
    int i00s[4], boffs[4];
    float wxs[4], wys[4];
    #pragma unroll
    for (int s = 0; s < 4; ++s) {
        int o = s * 64 + lane; if (o > 195) o = 195;
        int ji = o >> 2, cl4 = o & 3;
        int j = (ji * 37) >> 8;       // floor(ji/7) for ji<49
        int i2 = ji - j * 7;
        float yv = base + j * STEP;
        float xv = base + i2 * STEP;
        float y0f = floorf(yv), x0f = floorf(xv);
        wys[s] = yv - y0f; wxs[s] = xv - x0f;
        i00s[s] = cl4 * 197 + (int)y0f * 14 + (int)x0f;
        boffs[s] = ((ji << 9) + (ch0 << 4) + (wv << 2) + cl4) * 12;
    }

    const float4* srcb = (const float4*)proj + (size_t)n * CHW4 + ch0 * 784 + wv * 196;
    float acc[10];
    #pragma unroll
    for (int k = 0; k < 10; ++k) acc[k] = 0.f;

    float4 v0, v1, v2, v3;
    // prologue: proj chunk 0 -> buffer 0
    {
        v0 = srcb[lane]; v1 = srcb[lane + 64]; v2 = srcb[lane + 128];
        if (l4) v3 = srcb[lane + 192];
        float* xw = &X[wv][0][0];
        *(float4*)&xw[cc0 * 197 + q0 * 4] = v0;
        *(float4*)&xw[cc1 * 197 + q1 * 4] = v1;
        *(float4*)&xw[cc2 * 197 + q2 * 4] = v2;
        if (l4) *(float4*)&xw[3 * 197 + q3 * 4] = v3;
    }

#define SLOT(S, Ca, Cb, Cc) do { \
    int i00_ = i00s[S]; \
    float v00 = xb[i00_],      v01 = xb[i00_ + 1]; \
    float v10 = xb[i00_ + 14], v11 = xb[i00_ + 15]; \
    float top = v00 + (v01 - v00) * wxs[S]; \
    float bot = v10 + (v11 - v10) * wxs[S]; \
    float v_ = top + (bot - top) * wys[S]; \
    acc[0] += v_ * Ca.x; acc[1] += v_ * Ca.y; acc[2] += v_ * Ca.z; acc[3] += v_ * Ca.w; \
    acc[4] += v_ * Cb.x; acc[5] += v_ * Cb.y; acc[6] += v_ * Cb.z; acc[7] += v_ * Cb.w; \
    acc[8] += v_ * Cc.x; acc[9] += v_ * Cc.y; \
} while (0)

    #pragma unroll 1
    for (int t = 0; t < 16; ++t) {
        // 1) coeff loads for chunk t (ISSUED FIRST: their use won't drain proj)
        int tof = t * 192;
        const float* bp0 = Bt + boffs[0] + tof;
        float4 c00 = *(const float4*)bp0;
        float4 c01 = *(const float4*)(bp0 + 4);
        float4 c02 = *(const float4*)(bp0 + 8);
        const float* bp1 = Bt + boffs[1] + tof;
        float4 c10 = *(const float4*)bp1;
        float4 c11 = *(const float4*)(bp1 + 4);
        float4 c12 = *(const float4*)(bp1 + 8);
        const float* bp2 = Bt + boffs[2] + tof;
        float4 c20 = *(const float4*)bp2;
        float4 c21 = *(const float4*)(bp2 + 4);
        float4 c22 = *(const float4*)(bp2 + 8);
        float4 c30, c31, c32;
        if (l4) {
            const float* bp3 = Bt + boffs[3] + tof;
            c30 = *(const float4*)bp3;
            c31 = *(const float4*)(bp3 + 4);
            c32 = *(const float4*)(bp3 + 8);
        }
        // 2) proj loads for chunk t+1 (younger than coeffs in vmcnt FIFO)
        if (t < 15) {
            const float4* sn = srcb + (t + 1) * 784;
            v0 = sn[lane]; v1 = sn[lane + 64]; v2 = sn[lane + 128];
            if (l4) v3 = sn[lane + 192];
        }
        __builtin_amdgcn_sched_barrier(0);
        // 3) compute chunk t: LDS + registers only
        const float* xb = &X[wv][t & 1][0];
        SLOT(0, c00, c01, c02);
        SLOT(1, c10, c11, c12);
        SLOT(2, c20, c21, c22);
        if (l4) SLOT(3, c30, c31, c32);
        // 4) scatter chunk t+1 into the other private buffer (waits proj only)
        if (t < 15) {
            float* xw = &X[wv][(t + 1) & 1][0];
            *(float4*)&xw[cc0 * 197 + q0 * 4] = v0;
            *(float4*)&xw[cc1 * 197 + q1 * 4] = v1;
            *(float4*)&xw[cc2 * 197 + q2 * 4] = v2;
            if (l4) *(float4*)&xw[3 * 197 + q3 * 4] = v3;
        }
    }
#undef SLOT

    #pragma unroll
    for (int k = 0; k < 10; ++k) {
        float v = acc[k];
        v += __shfl_xor(v, 1);
        v += __shfl_xor(v, 2);
        v += __shfl_xor(v, 4);
        v += __shfl_xor(v, 8);
        v += __shfl_xor(v, 16);
        v += __shfl_xor(v, 32);
        if (lane == k) part[((size_t)b * 4 + wv) * 10 + k] = v;
    }
}

// out[n,k] = bias + dpart-sum + 8 wave-partials (2 halves x 4 waves)
__global__ void k_reduce(const float* __restrict__ part,
                         const float* __restrict__ dpart,
                         const float* __restrict__ b_note, const float* __restrict__ b_reg,
                         float* __restrict__ out) {
    int idx = blockIdx.x * 256 + threadIdx.x;  // 0..5119
    int n = idx / 10, k = idx % 10;
    float s = (k < 2) ? b_note[k] : b_reg[k - 2];
    for (int b = 0; b < 8; ++b) s += dpart[k * 8 + b];
    #pragma unroll
    for (int h = 0; h < 2; ++h)
        for (int w = 0; w < 4; ++w)
            s += part[(((size_t)(n * 2 + h)) * 4 + w) * 10 + k];
    if (k < 2) out[n * 2 + k] = s;
    else       out[1024 + n * 8 + (k - 2)] = s;
}

extern "C" void kernel_launch(void* const* d_in, const int* in_sizes, int n_in,
                              void* d_out, int out_size, void* d_ws, size_t ws_size,
                              hipStream_t stream) {
    const float* proj   = (const float*)d_in[0];
    const float* w1     = (const float*)d_in[1];
    const float* b1     = (const float*)d_in[2];
    const float* w2     = (const float*)d_in[3];
    const float* b2     = (const float*)d_in[4];
    const float* w3     = (const float*)d_in[5];
    const float* b3     = (const float*)d_in[6];
    const float* w_note = (const float*)d_in[7];
    const float* b_note = (const float*)d_in[8];
    const float* w_reg  = (const float*)d_in[9];
    const float* b_reg  = (const float*)d_in[10];

    float* ws    = (float*)d_ws;
    float* WH    = ws;
    float* Y     = WH + 250880;
    float* T1    = Y + 262144;
    float* Bt    = T1 + 250880;
    float* u2    = Bt + 301056;
    float* vv    = u2 + 512;
    float* dpart = vv + 512;
    float* part  = dpart + 80;
    float* out   = (float*)d_out;

    k_prep1<<<554, 512, 0, stream>>>(w_note, w_reg, w2, b1, b2, WH, u2);
    k_prep2<<<640, 256, 0, stream>>>(w1, w2, w3, WH, u2, b3, Y, T1, vv);
    k_prep3<<<336, 256, 0, stream>>>(T1, Y, w_note, w_reg, vv, Bt, dpart);
    k_mainf<<<1024, 256, 0, stream>>>(proj, Bt, part);
    k_reduce<<<20, 256, 0, stream>>>(part, dpart, b_note, b_reg, out);
}

// Round 20
// 93.834 us; speedup vs baseline: 1.0977x; 1.0977x over previous
//
#include <hip/hip_runtime.h>

// out[n,k] = d[k] + sum_{ji,c} Bmat[k*49+ji][c] * bilinear_ji(proj[n,c,:,:])
// Bmat = WH·(w3·w2·w1); boxes constant -> pipeline fully linear in proj.
//
// k_mainf = round-16 winner with ONE change: per chunk, Bmat coeff loads are
// issued BEFORE the next-chunk proj loads (vmcnt FIFO: coeff use waits only
// vmcnt(4); proj prefetch survives the whole compute phase).
//
// ws layout (floats):
//   WH    [490][512]   off 0
//   Y     [512][512]   off 250880
//   T1    [490][512]   off 513024
//   Bmat  [490][512]   off 763904
//   u2    [512]        off 1014784
//   vv    [512]        off 1015296
//   dpart [10][8]      off 1015808
//   part  [1024*4][10] off 1015888

#define CHW4 25088   // float4 per proj row
#define STEP 1.8571428571428572f  // 13/7

// ---------- prep level 1: WH transpose (blocks 0..489) + u2=b2+w2*b1 (490..553)
__global__ __launch_bounds__(512) void k_prep1(
    const float* __restrict__ w_note, const float* __restrict__ w_reg,
    const float* __restrict__ w2, const float* __restrict__ b1,
    const float* __restrict__ b2,
    float* __restrict__ WH, float* __restrict__ u2) {
    int blk = blockIdx.x;
    int tid = threadIdx.x;
    if (blk < 490) {
        int k = blk / 49, ji = blk % 49;
        const float* wh = (k < 2) ? (w_note + k * 25088) : (w_reg + (k - 2) * 25088);
        WH[(size_t)blk * 512 + tid] = wh[tid * 49 + ji];
    } else {
        int wv = tid >> 6, lane = tid & 63;
        int o = (blk - 490) * 8 + wv;
        float s = 0.f;
        #pragma unroll
        for (int r = 0; r < 8; ++r) s += w2[(size_t)o * 512 + lane + r * 64] * b1[lane + r * 64];
        for (int off = 32; off; off >>= 1) s += __shfl_down(s, off);
        if (lane == 0) u2[o] = b2[o] + s;
    }
}

// ---------- prep level 2: {Y=w2*w1 | T1=WH*w3} (0..511) + vv=b3+w3*u2 (512..639)
__global__ __launch_bounds__(256) void k_prep2(
    const float* __restrict__ w1, const float* __restrict__ w2,
    const float* __restrict__ w3, const float* __restrict__ WH,
    const float* __restrict__ u2, const float* __restrict__ b3,
    float* __restrict__ Y, float* __restrict__ T1, float* __restrict__ vv) {
    int blk = blockIdx.x;
    int tid = threadIdx.x;
    if (blk < 512) {
        __shared__ float As[32][36];
        __shared__ float Bs[32][36];
        const float* A; const float* B; float* C; int M;
        if (blk < 256) { A = w2; B = w1; C = Y;  M = 512; }
        else           { A = WH; B = w3; C = T1; M = 490; }
        int t = blk & 255;
        int bx = t & 15, by = t >> 4;
        int lr = tid >> 3, lc = (tid & 7) << 2;
        int tx = tid & 15, ty = tid >> 4;
        float a00 = 0.f, a01 = 0.f, a10 = 0.f, a11 = 0.f;
        for (int kc = 0; kc < 512; kc += 32) {
            int gr = by * 32 + lr;
            float4 av = make_float4(0.f, 0.f, 0.f, 0.f);
            if (gr < M) av = *(const float4*)&A[(size_t)gr * 512 + kc + lc];
            *(float4*)&As[lr][lc] = av;
            *(float4*)&Bs[lr][lc] = *(const float4*)&B[(size_t)(kc + lr) * 512 + bx * 32 + lc];
            __syncthreads();
            #pragma unroll
            for (int kk = 0; kk < 32; ++kk) {
                float b0 = Bs[kk][tx * 2], b1v = Bs[kk][tx * 2 + 1];
                float x0 = As[ty * 2][kk], x1 = As[ty * 2 + 1][kk];
                a00 += x0 * b0; a01 += x0 * b1v;
                a10 += x1 * b0; a11 += x1 * b1v;
            }
            __syncthreads();
        }
        int r0 = by * 32 + ty * 2, c0 = bx * 32 + tx * 2;
        if (r0 < M)     { C[(size_t)r0 * 512 + c0] = a00; C[(size_t)r0 * 512 + c0 + 1] = a01; }
        if (r0 + 1 < M) { C[(size_t)(r0 + 1) * 512 + c0] = a10; C[(size_t)(r0 + 1) * 512 + c0 + 1] = a11; }
    } else {
        int wv = tid >> 6, lane = tid & 63;
        int o = (blk - 512) * 4 + wv;
        float s = 0.f;
        #pragma unroll
        for (int r = 0; r < 8; ++r) s += w3[(size_t)o * 512 + lane + r * 64] * u2[lane + r * 64];
        for (int off = 32; off; off >>= 1) s += __shfl_down(s, off);
        if (lane == 0) vv[o] = b3[o] + s;
    }
}

// ---------- prep level 3: Bmat=T1*Y (0..255) + dpart (256..335)
__global__ __launch_bounds__(256) void k_prep3(
    const float* __restrict__ T1, const float* __restrict__ Y,
    const float* __restrict__ w_note, const float* __restrict__ w_reg,
    const float* __restrict__ vv,
    float* __restrict__ Bmat, float* __restrict__ dpart) {
    int blk = blockIdx.x;
    int tid = threadIdx.x;
    if (blk < 256) {
        __shared__ float As[32][36];
        __shared__ float Bs[32][36];
        int bx = blk & 15, by = blk >> 4;
        int lr = tid >> 3, lc = (tid & 7) << 2;
        int tx = tid & 15, ty = tid >> 4;
        int gr = by * 32 + lr;
        float a00 = 0.f, a01 = 0.f, a10 = 0.f, a11 = 0.f;
        for (int kc = 0; kc < 512; kc += 32) {
            float4 av = make_float4(0.f, 0.f, 0.f, 0.f);
            if (gr < 490) av = *(const float4*)&T1[(size_t)gr * 512 + kc + lc];
            *(float4*)&As[lr][lc] = av;
            *(float4*)&Bs[lr][lc] = *(const float4*)&Y[(size_t)(kc + lr) * 512 + bx * 32 + lc];
            __syncthreads();
            #pragma unroll
            for (int kk = 0; kk < 32; ++kk) {
                float b0 = Bs[kk][tx * 2], b1v = Bs[kk][tx * 2 + 1];
                float x0 = As[ty * 2][kk], x1 = As[ty * 2 + 1][kk];
                a00 += x0 * b0; a01 += x0 * b1v;
                a10 += x1 * b0; a11 += x1 * b1v;
            }
            __syncthreads();
        }
        int r0 = by * 32 + ty * 2, c0 = bx * 32 + tx * 2;
        if (r0 < 490)     { Bmat[(size_t)r0 * 512 + c0] = a00; Bmat[(size_t)r0 * 512 + c0 + 1] = a01; }
        if (r0 + 1 < 490) { Bmat[(size_t)(r0 + 1) * 512 + c0] = a10; Bmat[(size_t)(r0 + 1) * 512 + c0 + 1] = a11; }
    } else {
        int t = blk - 256;             // 0..79
        int k = t >> 3, b8 = t & 7;
        const float* wh = (k < 2) ? (w_note + k * 25088) : (w_reg + (k - 2) * 25088);
        float s = 0.f;
        for (int i = b8 * 256 + tid; i < 25088; i += 2048) s += wh[i] * vv[i / 49];
        __shared__ float red[256];
        red[tid] = s;
        __syncthreads();
        for (int off = 128; off; off >>= 1) {
            if (tid < off) red[tid] += red[tid + off];
            __syncthreads();
        }
        if (tid == 0) dpart[k * 8 + b8] = red[0];
    }
}

// ---------- fused main: r16 structure + coeff-before-proj issue order
__global__ __launch_bounds__(256) void k_mainf(const float* __restrict__ proj,
                                               const float* __restrict__ Bmat,
                                               float* __restrict__ part) {
    __shared__ float X[2][16][197];   // 25,216 B
    int b = blockIdx.x;               // 0..1023
    int n = b >> 1;
    int ch0 = (b & 1) << 4;           // chunk ch = ch0 + t
    int tid = threadIdx.x;
    int wv = tid >> 6, lane = tid & 63;

    // chunk-invariant staging scatter coords: i = tid + s*256 = cc*49 + q
    int cc0 = tid / 49,            q0 = tid - (tid / 49) * 49;
    int cc1 = cc0 + 5,             q1 = q0 + 11; if (q1 >= 49) { q1 -= 49; ++cc1; }
    int cc2 = cc1 + 5,             q2 = q1 + 11; if (q2 >= 49) { q2 -= 49; ++cc2; }

    // chunk-invariant bilinear coords + Bmat column bases
    const float base = STEP * 0.5f - 0.5f;
    int   i00s[4], bidx0s[4];
    float wxs[4], wys[4];
    #pragma unroll
    for (int s = 0; s < 4; ++s) {
        int o = tid + s * 256;
        if (o > 783) o = 783;          // dummy for inactive tail lanes
        int ji = o >> 4, cl = o & 15;
        int j = (ji * 37) >> 8;        // floor(ji/7) for ji<49
        int i2 = ji - j * 7;
        float yv = base + j * STEP;
        float xv = base + i2 * STEP;
        float y0f = floorf(yv), x0f = floorf(xv);
        wys[s] = yv - y0f; wxs[s] = xv - x0f;
        i00s[s] = cl * 197 + (int)y0f * 14 + (int)x0f;
        bidx0s[s] = (ji << 9) + (ch0 << 4) + cl;   // + (t<<4) at use
    }

    const float4* src0 = (const float4*)proj + (size_t)n * CHW4 + ch0 * 784;
    float acc[10];
    #pragma unroll
    for (int k = 0; k < 10; ++k) acc[k] = 0.f;

    // prologue: stage chunk 0 into buf 0
    {
        float4 v0 = src0[tid];
        float4 v1 = src0[tid + 256];
        float4 v2 = src0[tid + 512];
        float* xb = &X[0][0][0];
        *(float4*)&xb[cc0 * 197 + q0 * 4] = v0;
        *(float4*)&xb[cc1 * 197 + q1 * 4] = v1;
        *(float4*)&xb[cc2 * 197 + q2 * 4] = v2;
        if (tid < 16) *(float4*)&xb[15 * 197 + (tid + 33) * 4] = src0[tid + 768];
    }
    __syncthreads();

    int cur = 0;
    #pragma unroll 1
    for (int t = 0; t < 16; ++t) {
        // 1) coeff loads for chunk t — OLDEST in the vmcnt FIFO
        float c0r[10], c1r[10], c2r[10], c3r[10];
        {
            const float* Bp0 = Bmat + bidx0s[0] + (t << 4);
            const float* Bp1 = Bmat + bidx0s[1] + (t << 4);
            const float* Bp2 = Bmat + bidx0s[2] + (t << 4);
            #pragma unroll
            for (int k = 0; k < 10; ++k) c0r[k] = Bp0[(size_t)k * 25088];
            #pragma unroll
            for (int k = 0; k < 10; ++k) c1r[k] = Bp1[(size_t)k * 25088];
            #pragma unroll
            for (int k = 0; k < 10; ++k) c2r[k] = Bp2[(size_t)k * 25088];
            if (tid < 16) {
                const float* Bp3 = Bmat + bidx0s[3] + (t << 4);
                #pragma unroll
                for (int k = 0; k < 10; ++k) c3r[k] = Bp3[(size_t)k * 25088];
            }
        }
        __builtin_amdgcn_sched_barrier(0);
        // 2) proj loads for chunk t+1 — YOUNGER (survive coeff waits)
        float4 v0, v1, v2, v3;
        if (t < 15) {
            const float4* sn = src0 + (t + 1) * 784;
            v0 = sn[tid]; v1 = sn[tid + 256]; v2 = sn[tid + 512];
            if (tid < 16) v3 = sn[tid + 768];
        }
        __builtin_amdgcn_sched_barrier(0);
        // 3) compute chunk t: LDS + coeff registers only
        const float* xb = &X[cur][0][0];
        {
            int i00 = i00s[0];
            float v00 = xb[i00],      v01 = xb[i00 + 1];
            float v10 = xb[i00 + 14], v11 = xb[i00 + 15];
            float top = v00 + (v01 - v00) * wxs[0];
            float bot = v10 + (v11 - v10) * wxs[0];
            float v = top + (bot - top) * wys[0];
            #pragma unroll
            for (int k = 0; k < 10; ++k) acc[k] += v * c0r[k];
        }
        {
            int i00 = i00s[1];
            float v00 = xb[i00],      v01 = xb[i00 + 1];
            float v10 = xb[i00 + 14], v11 = xb[i00 + 15];
            float top = v00 + (v01 - v00) * wxs[1];
            float bot = v10 + (v11 - v10) * wxs[1];
            float v = top + (bot - top) * wys[1];
            #pragma unroll
            for (int k = 0; k < 10; ++k) acc[k] += v * c1r[k];
        }
        {
            int i00 = i00s[2];
            float v00 = xb[i00],      v01 = xb[i00 + 1];
            float v10 = xb[i00 + 14], v11 = xb[i00 + 15];
            float top = v00 + (v01 - v00) * wxs[2];
            float bot = v10 + (v11 - v10) * wxs[2];
            float v = top + (bot - top) * wys[2];
            #pragma unroll
            for (int k = 0; k < 10; ++k) acc[k] += v * c2r[k];
        }
        if (tid < 16) {
            int i00 = i00s[3];
            float v00 = xb[i00],      v01 = xb[i00 + 1];
            float v10 = xb[i00 + 14], v11 = xb[i00 + 15];
            float top = v00 + (v01 - v00) * wxs[3];
            float bot = v10 + (v11 - v10) * wxs[3];
            float v = top + (bot - top) * wys[3];
            #pragma unroll
            for (int k = 0; k < 10; ++k) acc[k] += v * c3r[k];
        }
        // 4) scatter chunk t+1 into the other buffer
        if (t < 15) {
            float* xw = &X[cur ^ 1][0][0];
            *(float4*)&xw[cc0 * 197 + q0 * 4] = v0;
            *(float4*)&xw[cc1 * 197 + q1 * 4] = v1;
            *(float4*)&xw[cc2 * 197 + q2 * 4] = v2;
            if (tid < 16) *(float4*)&xw[15 * 197 + (tid + 33) * 4] = v3;
        }
        __syncthreads();
        cur ^= 1;
    }

    #pragma unroll
    for (int k = 0; k < 10; ++k) {
        float v = acc[k];
        v += __shfl_xor(v, 1);
        v += __shfl_xor(v, 2);
        v += __shfl_xor(v, 4);
        v += __shfl_xor(v, 8);
        v += __shfl_xor(v, 16);
        v += __shfl_xor(v, 32);
        if (lane == k) part[((size_t)b * 4 + wv) * 10 + k] = v;
    }
}

// out[n,k] = bias + dpart-sum + 8 wave-partials (2 halves x 4 waves)
__global__ void k_reduce(const float* __restrict__ part,
                         const float* __restrict__ dpart,
                         const float* __restrict__ b_note, const float* __restrict__ b_reg,
                         float* __restrict__ out) {
    int idx = blockIdx.x * 256 + threadIdx.x;  // 0..5119
    int n = idx / 10, k = idx % 10;
    float s = (k < 2) ? b_note[k] : b_reg[k - 2];
    for (int b = 0; b < 8; ++b) s += dpart[k * 8 + b];
    #pragma unroll
    for (int h = 0; h < 2; ++h)
        for (int w = 0; w < 4; ++w)
            s += part[(((size_t)(n * 2 + h)) * 4 + w) * 10 + k];
    if (k < 2) out[n * 2 + k] = s;
    else       out[1024 + n * 8 + (k - 2)] = s;
}

extern "C" void kernel_launch(void* const* d_in, const int* in_sizes, int n_in,
                              void* d_out, int out_size, void* d_ws, size_t ws_size,
                              hipStream_t stream) {
    const float* proj   = (const float*)d_in[0];
    const float* w1     = (const float*)d_in[1];
    const float* b1     = (const float*)d_in[2];
    const float* w2     = (const float*)d_in[3];
    const float* b2     = (const float*)d_in[4];
    const float* w3     = (const float*)d_in[5];
    const float* b3     = (const float*)d_in[6];
    const float* w_note = (const float*)d_in[7];
    const float* b_note = (const float*)d_in[8];
    const float* w_reg  = (const float*)d_in[9];
    const float* b_reg  = (const float*)d_in[10];

    float* ws    = (float*)d_ws;
    float* WH    = ws;
    float* Y     = WH + 250880;
    float* T1    = Y + 262144;
    float* Bmat  = T1 + 250880;
    float* u2    = Bmat + 250880;
    float* vv    = u2 + 512;
    float* dpart = vv + 512;
    float* part  = dpart + 80;
    float* out   = (float*)d_out;

    k_prep1<<<554, 512, 0, stream>>>(w_note, w_reg, w2, b1, b2, WH, u2);
    k_prep2<<<640, 256, 0, stream>>>(w1, w2, w3, WH, u2, b3, Y, T1, vv);
    k_prep3<<<336, 256, 0, stream>>>(T1, Y, w_note, w_reg, vv, Bmat, dpart);
    k_mainf<<<1024, 256, 0, stream>>>(proj, Bmat, part);
    k_reduce<<<20, 256, 0, stream>>>(part, dpart, b_note, b_reg, out);
}

// Round 21
// 83.793 us; speedup vs baseline: 1.2293x; 1.1198x over previous
//
#include <hip/hip_runtime.h>

// out[n,k] = d[k] + sum_{ji,c} Bmat[k*49+ji][c] * bilinear_ji(proj[n,c,:,:])
// Bmat = WH·(w3·w2·w1); boxes constant -> pipeline fully linear in proj.
//
// k_mainf v4 = r20 winner + N-PAIRING: block = (n-pair, half); one thread
// computes acc[2][10] for rows n,n+1 so each chunk's coeff registers are
// loaded ONCE for both rows (coeff traffic 514 -> 257 MB, -36% of total
// delivered bytes). Proj stays two contiguous 100 KB streams per block.
// Same double-buffer + coeff-before-proj vmcnt ordering as r20.
//
// ws layout (floats):
//   WH    [490][512]   off 0
//   Y     [512][512]   off 250880
//   T1    [490][512]   off 513024
//   Bmat  [490][512]   off 763904
//   u2    [512]        off 1014784
//   vv    [512]        off 1015296
//   dpart [10][8]      off 1015808
//   part  [512*4][2][10] off 1015888

#define CHW4 25088   // float4 per proj row
#define STEP 1.8571428571428572f  // 13/7

// ---------- prep level 1: WH transpose (blocks 0..489) + u2=b2+w2*b1 (490..553)
__global__ __launch_bounds__(512) void k_prep1(
    const float* __restrict__ w_note, const float* __restrict__ w_reg,
    const float* __restrict__ w2, const float* __restrict__ b1,
    const float* __restrict__ b2,
    float* __restrict__ WH, float* __restrict__ u2) {
    int blk = blockIdx.x;
    int tid = threadIdx.x;
    if (blk < 490) {
        int k = blk / 49, ji = blk % 49;
        const float* wh = (k < 2) ? (w_note + k * 25088) : (w_reg + (k - 2) * 25088);
        WH[(size_t)blk * 512 + tid] = wh[tid * 49 + ji];
    } else {
        int wv = tid >> 6, lane = tid & 63;
        int o = (blk - 490) * 8 + wv;
        float s = 0.f;
        #pragma unroll
        for (int r = 0; r < 8; ++r) s += w2[(size_t)o * 512 + lane + r * 64] * b1[lane + r * 64];
        for (int off = 32; off; off >>= 1) s += __shfl_down(s, off);
        if (lane == 0) u2[o] = b2[o] + s;
    }
}

// ---------- prep level 2: {Y=w2*w1 | T1=WH*w3} (0..511) + vv=b3+w3*u2 (512..639)
__global__ __launch_bounds__(256) void k_prep2(
    const float* __restrict__ w1, const float* __restrict__ w2,
    const float* __restrict__ w3, const float* __restrict__ WH,
    const float* __restrict__ u2, const float* __restrict__ b3,
    float* __restrict__ Y, float* __restrict__ T1, float* __restrict__ vv) {
    int blk = blockIdx.x;
    int tid = threadIdx.x;
    if (blk < 512) {
        __shared__ float As[32][36];
        __shared__ float Bs[32][36];
        const float* A; const float* B; float* C; int M;
        if (blk < 256) { A = w2; B = w1; C = Y;  M = 512; }
        else           { A = WH; B = w3; C = T1; M = 490; }
        int t = blk & 255;
        int bx = t & 15, by = t >> 4;
        int lr = tid >> 3, lc = (tid & 7) << 2;
        int tx = tid & 15, ty = tid >> 4;
        float a00 = 0.f, a01 = 0.f, a10 = 0.f, a11 = 0.f;
        for (int kc = 0; kc < 512; kc += 32) {
            int gr = by * 32 + lr;
            float4 av = make_float4(0.f, 0.f, 0.f, 0.f);
            if (gr < M) av = *(const float4*)&A[(size_t)gr * 512 + kc + lc];
            *(float4*)&As[lr][lc] = av;
            *(float4*)&Bs[lr][lc] = *(const float4*)&B[(size_t)(kc + lr) * 512 + bx * 32 + lc];
            __syncthreads();
            #pragma unroll
            for (int kk = 0; kk < 32; ++kk) {
                float b0 = Bs[kk][tx * 2], b1v = Bs[kk][tx * 2 + 1];
                float x0 = As[ty * 2][kk], x1 = As[ty * 2 + 1][kk];
                a00 += x0 * b0; a01 += x0 * b1v;
                a10 += x1 * b0; a11 += x1 * b1v;
            }
            __syncthreads();
        }
        int r0 = by * 32 + ty * 2, c0 = bx * 32 + tx * 2;
        if (r0 < M)     { C[(size_t)r0 * 512 + c0] = a00; C[(size_t)r0 * 512 + c0 + 1] = a01; }
        if (r0 + 1 < M) { C[(size_t)(r0 + 1) * 512 + c0] = a10; C[(size_t)(r0 + 1) * 512 + c0 + 1] = a11; }
    } else {
        int wv = tid >> 6, lane = tid & 63;
        int o = (blk - 512) * 4 + wv;
        float s = 0.f;
        #pragma unroll
        for (int r = 0; r < 8; ++r) s += w3[(size_t)o * 512 + lane + r * 64] * u2[lane + r * 64];
        for (int off = 32; off; off >>= 1) s += __shfl_down(s, off);
        if (lane == 0) vv[o] = b3[o] + s;
    }
}

// ---------- prep level 3: Bmat=T1*Y (0..255) + dpart (256..335)
__global__ __launch_bounds__(256) void k_prep3(
    const float* __restrict__ T1, const float* __restrict__ Y,
    const float* __restrict__ w_note, const float* __restrict__ w_reg,
    const float* __restrict__ vv,
    float* __restrict__ Bmat, float* __restrict__ dpart) {
    int blk = blockIdx.x;
    int tid = threadIdx.x;
    if (blk < 256) {
        __shared__ float As[32][36];
        __shared__ float Bs[32][36];
        int bx = blk & 15, by = blk >> 4;
        int lr = tid >> 3, lc = (tid & 7) << 2;
        int tx = tid & 15, ty = tid >> 4;
        int gr = by * 32 + lr;
        float a00 = 0.f, a01 = 0.f, a10 = 0.f, a11 = 0.f;
        for (int kc = 0; kc < 512; kc += 32) {
            float4 av = make_float4(0.f, 0.f, 0.f, 0.f);
            if (gr < 490) av = *(const float4*)&T1[(size_t)gr * 512 + kc + lc];
            *(float4*)&As[lr][lc] = av;
            *(float4*)&Bs[lr][lc] = *(const float4*)&Y[(size_t)(kc + lr) * 512 + bx * 32 + lc];
            __syncthreads();
            #pragma unroll
            for (int kk = 0; kk < 32; ++kk) {
                float b0 = Bs[kk][tx * 2], b1v = Bs[kk][tx * 2 + 1];
                float x0 = As[ty * 2][kk], x1 = As[ty * 2 + 1][kk];
                a00 += x0 * b0; a01 += x0 * b1v;
                a10 += x1 * b0; a11 += x1 * b1v;
            }
            __syncthreads();
        }
        int r0 = by * 32 + ty * 2, c0 = bx * 32 + tx * 2;
        if (r0 < 490)     { Bmat[(size_t)r0 * 512 + c0] = a00; Bmat[(size_t)r0 * 512 + c0 + 1] = a01; }
        if (r0 + 1 < 490) { Bmat[(size_t)(r0 + 1) * 512 + c0] = a10; Bmat[(size_t)(r0 + 1) * 512 + c0 + 1] = a11; }
    } else {
        int t = blk - 256;             // 0..79
        int k = t >> 3, b8 = t & 7;
        const float* wh = (k < 2) ? (w_note + k * 25088) : (w_reg + (k - 2) * 25088);
        float s = 0.f;
        for (int i = b8 * 256 + tid; i < 25088; i += 2048) s += wh[i] * vv[i / 49];
        __shared__ float red[256];
        red[tid] = s;
        __syncthreads();
        for (int off = 128; off; off >>= 1) {
            if (tid < off) red[tid] += red[tid + off];
            __syncthreads();
        }
        if (tid == 0) dpart[k * 8 + b8] = red[0];
    }
}

// ---------- fused main v4: r20 + n-pairing (coeffs shared across 2 rows)
__global__ __launch_bounds__(256) void k_mainf(const float* __restrict__ proj,
                                               const float* __restrict__ Bmat,
                                               float* __restrict__ part) {
    __shared__ float X[2][2][16][197];  // [n-sel][buf][ch][..] = 50,432 B
    int b = blockIdx.x;                 // 0..511
    int np = b >> 1;                    // n-pair: rows 2*np, 2*np+1
    int ch0 = (b & 1) << 4;             // chunk ch = ch0 + t
    int tid = threadIdx.x;
    int wv = tid >> 6, lane = tid & 63;

    // chunk-invariant staging scatter coords: i = tid + s*256 = cc*49 + q
    int cc0 = tid / 49,            q0 = tid - (tid / 49) * 49;
    int cc1 = cc0 + 5,             q1 = q0 + 11; if (q1 >= 49) { q1 -= 49; ++cc1; }
    int cc2 = cc1 + 5,             q2 = q1 + 11; if (q2 >= 49) { q2 -= 49; ++cc2; }

    // chunk-invariant bilinear coords + Bmat column bases
    const float base = STEP * 0.5f - 0.5f;
    int   i00s[4], bidx0s[4];
    float wxs[4], wys[4];
    #pragma unroll
    for (int s = 0; s < 4; ++s) {
        int o = tid + s * 256;
        if (o > 783) o = 783;
        int ji = o >> 4, cl = o & 15;
        int j = (ji * 37) >> 8;
        int i2 = ji - j * 7;
        float yv = base + j * STEP;
        float xv = base + i2 * STEP;
        float y0f = floorf(yv), x0f = floorf(xv);
        wys[s] = yv - y0f; wxs[s] = xv - x0f;
        i00s[s] = cl * 197 + (int)y0f * 14 + (int)x0f;
        bidx0s[s] = (ji << 9) + (ch0 << 4) + cl;   // + (t<<4) at use
    }

    const float4* srcA = (const float4*)proj + (size_t)(np * 2) * CHW4 + ch0 * 784;
    const float4* srcB = srcA + CHW4;
    float acc[2][10];
    #pragma unroll
    for (int j = 0; j < 2; ++j)
        #pragma unroll
        for (int k = 0; k < 10; ++k) acc[j][k] = 0.f;

    // prologue: stage chunk 0 (both rows) into buf 0
    {
        float4 a0 = srcA[tid], a1 = srcA[tid + 256], a2 = srcA[tid + 512];
        float4 b0 = srcB[tid], b1 = srcB[tid + 256], b2 = srcB[tid + 512];
        float* xa = &X[0][0][0][0];
        float* xb = &X[1][0][0][0];
        *(float4*)&xa[cc0 * 197 + q0 * 4] = a0;
        *(float4*)&xa[cc1 * 197 + q1 * 4] = a1;
        *(float4*)&xa[cc2 * 197 + q2 * 4] = a2;
        *(float4*)&xb[cc0 * 197 + q0 * 4] = b0;
        *(float4*)&xb[cc1 * 197 + q1 * 4] = b1;
        *(float4*)&xb[cc2 * 197 + q2 * 4] = b2;
        if (tid < 16) {
            *(float4*)&xa[15 * 197 + (tid + 33) * 4] = srcA[tid + 768];
            *(float4*)&xb[15 * 197 + (tid + 33) * 4] = srcB[tid + 768];
        }
    }
    __syncthreads();

    int cur = 0;
    #pragma unroll 1
    for (int t = 0; t < 16; ++t) {
        // 1) coeff loads for chunk t — OLDEST in the vmcnt FIFO (shared by both rows)
        float c0r[10], c1r[10], c2r[10], c3r[10];
        {
            const float* Bp0 = Bmat + bidx0s[0] + (t << 4);
            const float* Bp1 = Bmat + bidx0s[1] + (t << 4);
            const float* Bp2 = Bmat + bidx0s[2] + (t << 4);
            #pragma unroll
            for (int k = 0; k < 10; ++k) c0r[k] = Bp0[(size_t)k * 25088];
            #pragma unroll
            for (int k = 0; k < 10; ++k) c1r[k] = Bp1[(size_t)k * 25088];
            #pragma unroll
            for (int k = 0; k < 10; ++k) c2r[k] = Bp2[(size_t)k * 25088];
            if (tid < 16) {
                const float* Bp3 = Bmat + bidx0s[3] + (t << 4);
                #pragma unroll
                for (int k = 0; k < 10; ++k) c3r[k] = Bp3[(size_t)k * 25088];
            }
        }
        __builtin_amdgcn_sched_barrier(0);
        // 2) proj loads for chunk t+1 (both rows) — YOUNGER (survive coeff waits)
        float4 a0, a1, a2, a3, b0, b1, b2, b3;
        if (t < 15) {
            const float4* sa = srcA + (t + 1) * 784;
            const float4* sb = srcB + (t + 1) * 784;
            a0 = sa[tid]; a1 = sa[tid + 256]; a2 = sa[tid + 512];
            b0 = sb[tid]; b1 = sb[tid + 256]; b2 = sb[tid + 512];
            if (tid < 16) { a3 = sa[tid + 768]; b3 = sb[tid + 768]; }
        }
        __builtin_amdgcn_sched_barrier(0);
        // 3) compute chunk t for BOTH rows: LDS + coeff registers only
        const float* xa = &X[0][cur][0][0];
        const float* xb = &X[1][cur][0][0];
        #pragma unroll
        for (int s = 0; s < 3; ++s) {
            const float* cr = (s == 0) ? c0r : (s == 1) ? c1r : c2r;
            int i00 = i00s[s];
            float wxv = wxs[s], wyv = wys[s];
            float va00 = xa[i00],      va01 = xa[i00 + 1];
            float va10 = xa[i00 + 14], va11 = xa[i00 + 15];
            float ta = va00 + (va01 - va00) * wxv;
            float ba = va10 + (va11 - va10) * wxv;
            float va = ta + (ba - ta) * wyv;
            float vb00 = xb[i00],      vb01 = xb[i00 + 1];
            float vb10 = xb[i00 + 14], vb11 = xb[i00 + 15];
            float tb = vb00 + (vb01 - vb00) * wxv;
            float bb = vb10 + (vb11 - vb10) * wxv;
            float vb = tb + (bb - tb) * wyv;
            #pragma unroll
            for (int k = 0; k < 10; ++k) {
                acc[0][k] += va * cr[k];
                acc[1][k] += vb * cr[k];
            }
        }
        if (tid < 16) {
            int i00 = i00s[3];
            float wxv = wxs[3], wyv = wys[3];
            float va00 = xa[i00],      va01 = xa[i00 + 1];
            float va10 = xa[i00 + 14], va11 = xa[i00 + 15];
            float ta = va00 + (va01 - va00) * wxv;
            float ba = va10 + (va11 - va10) * wxv;
            float va = ta + (ba - ta) * wyv;
            float vb00 = xb[i00],      vb01 = xb[i00 + 1];
            float vb10 = xb[i00 + 14], vb11 = xb[i00 + 15];
            float tb = vb00 + (vb01 - vb00) * wxv;
            float bb = vb10 + (vb11 - vb10) * wxv;
            float vb = tb + (bb - tb) * wyv;
            #pragma unroll
            for (int k = 0; k < 10; ++k) {
                acc[0][k] += va * c3r[k];
                acc[1][k] += vb * c3r[k];
            }
        }
        // 4) scatter chunk t+1 (both rows) into the other buffers
        if (t < 15) {
            float* xwa = &X[0][cur ^ 1][0][0];
            float* xwb = &X[1][cur ^ 1][0][0];
            *(float4*)&xwa[cc0 * 197 + q0 * 4] = a0;
            *(float4*)&xwa[cc1 * 197 + q1 * 4] = a1;
            *(float4*)&xwa[cc2 * 197 + q2 * 4] = a2;
            *(float4*)&xwb[cc0 * 197 + q0 * 4] = b0;
            *(float4*)&xwb[cc1 * 197 + q1 * 4] = b1;
            *(float4*)&xwb[cc2 * 197 + q2 * 4] = b2;
            if (tid < 16) {
                *(float4*)&xwa[15 * 197 + (tid + 33) * 4] = a3;
                *(float4*)&xwb[15 * 197 + (tid + 33) * 4] = b3;
            }
        }
        __syncthreads();
        cur ^= 1;
    }

    #pragma unroll
    for (int j = 0; j < 2; ++j)
        #pragma unroll
        for (int k = 0; k < 10; ++k) {
            float v = acc[j][k];
            v += __shfl_xor(v, 1);
            v += __shfl_xor(v, 2);
            v += __shfl_xor(v, 4);
            v += __shfl_xor(v, 8);
            v += __shfl_xor(v, 16);
            v += __shfl_xor(v, 32);
            if (lane == j * 10 + k)
                part[(((size_t)b * 4 + wv) * 2 + j) * 10 + k] = v;
        }
}

// out[n,k]: n = 2*np+j; partials at [((np*2+h)*4+w)*2+j][k] for h=half,w=wave
__global__ void k_reduce(const float* __restrict__ part,
                         const float* __restrict__ dpart,
                         const float* __restrict__ b_note, const float* __restrict__ b_reg,
                         float* __restrict__ out) {
    int idx = blockIdx.x * 256 + threadIdx.x;  // 0..5119
    int n = idx / 10, k = idx % 10;
    int np = n >> 1, j = n & 1;
    float s = (k < 2) ? b_note[k] : b_reg[k - 2];
    for (int b8 = 0; b8 < 8; ++b8) s += dpart[k * 8 + b8];
    #pragma unroll
    for (int h = 0; h < 2; ++h)
        for (int w = 0; w < 4; ++w)
            s += part[((((size_t)(np * 2 + h)) * 4 + w) * 2 + j) * 10 + k];
    if (k < 2) out[n * 2 + k] = s;
    else       out[1024 + n * 8 + (k - 2)] = s;
}

extern "C" void kernel_launch(void* const* d_in, const int* in_sizes, int n_in,
                              void* d_out, int out_size, void* d_ws, size_t ws_size,
                              hipStream_t stream) {
    const float* proj   = (const float*)d_in[0];
    const float* w1     = (const float*)d_in[1];
    const float* b1     = (const float*)d_in[2];
    const float* w2     = (const float*)d_in[3];
    const float* b2     = (const float*)d_in[4];
    const float* w3     = (const float*)d_in[5];
    const float* b3     = (const float*)d_in[6];
    const float* w_note = (const float*)d_in[7];
    const float* b_note = (const float*)d_in[8];
    const float* w_reg  = (const float*)d_in[9];
    const float* b_reg  = (const float*)d_in[10];

    float* ws    = (float*)d_ws;
    float* WH    = ws;
    float* Y     = WH + 250880;
    float* T1    = Y + 262144;
    float* Bmat  = T1 + 250880;
    float* u2    = Bmat + 250880;
    float* vv    = u2 + 512;
    float* dpart = vv + 512;
    float* part  = dpart + 80;
    float* out   = (float*)d_out;

    k_prep1<<<554, 512, 0, stream>>>(w_note, w_reg, w2, b1, b2, WH, u2);
    k_prep2<<<640, 256, 0, stream>>>(w1, w2, w3, WH, u2, b3, Y, T1, vv);
    k_prep3<<<336, 256, 0, stream>>>(T1, Y, w_note, w_reg, vv, Bmat, dpart);
    k_mainf<<<512, 256, 0, stream>>>(proj, Bmat, part);
    k_reduce<<<20, 256, 0, stream>>>(part, dpart, b_note, b_reg, out);
}